// Round 4
// baseline (56.743 us; speedup 1.0000x reference)
//
#include <hip/hip_runtime.h>
#include <hip/hip_bf16.h>

// bottom (8,256,128,128) f32; w1 (256,1,3,3); a1,w2,b2 (256,)
// out: res (8,256,64,64) ++ pexp (8,256,64,64), f32.
// K=3 S=2 P=1 -> Ho=Wo=64.
// Pipelined: 512 blocks x 512 threads; each block does 4 consecutive planes.
// Plane k+1 is prefetched into REGISTERS while plane k is computed from LDS,
// so one 64 KiB LDS buffer suffices and 2 blocks co-reside per CU.

#define HW 16384       // 128*128
#define N_OUT 8388608  // 8*256*64*64
#define PPB 4          // planes per block

__device__ __forceinline__ float hw_log2(float x) { return __builtin_amdgcn_logf(x); }
__device__ __forceinline__ float hw_exp2(float x) { return __builtin_amdgcn_exp2f(x); }
__device__ __forceinline__ float hw_rcp(float x)  { return __builtin_amdgcn_rcpf(x); }

__global__ __launch_bounds__(512, 4) void fused_ppool_pipe(
    const float* __restrict__ bottom,
    const float* __restrict__ w1,   // (256,3,3)
    const float* __restrict__ a1,
    const float* __restrict__ w2,
    const float* __restrict__ b2,
    float* __restrict__ out) {
    __shared__ float plane[HW];     // 64 KiB, single buffer
    __shared__ float smax[8];

    const int t    = threadIdx.x;
    const int wid  = t >> 6;
    const int lane = t & 63;
    const int bc0  = blockIdx.x * PPB;

    // Prologue: plane 0 loads into registers (8 x float4 = 32 VGPR).
    float4 r[8];
    {
        const float4* s0 = reinterpret_cast<const float4*>(bottom + (size_t)bc0 * HW);
        #pragma unroll
        for (int k = 0; k < 8; ++k) r[k] = s0[t + k * 512];
    }
    float4* pl4 = reinterpret_cast<float4*>(plane);

    for (int pi = 0; pi < PPB; ++pi) {
        const int bc = bc0 + pi;
        const int c  = bc & 255;

        __syncthreads();            // all waves done reading LDS (prev plane)

        // Drain regs -> LDS; per-thread max from registers (no LDS re-read).
        float mx = 0.f;
        #pragma unroll
        for (int k = 0; k < 8; ++k) {
            float4 v = r[k];
            pl4[t + k * 512] = v;
            mx = fmaxf(mx, fmaxf(fmaxf(fabsf(v.x), fabsf(v.y)),
                                 fmaxf(fabsf(v.z), fabsf(v.w))));
        }

        // Prefetch next plane into registers (in flight during compute).
        if (pi + 1 < PPB) {
            const float4* sn = reinterpret_cast<const float4*>(bottom + (size_t)(bc + 1) * HW);
            #pragma unroll
            for (int k = 0; k < 8; ++k) r[k] = sn[t + k * 512];
        }

        // Block max reduce.
        #pragma unroll
        for (int off = 32; off; off >>= 1)
            mx = fmaxf(mx, __shfl_down(mx, off, 64));
        if (lane == 0) smax[wid] = mx;
        __syncthreads();            // plane data + smax visible to all
        float m = fmaxf(fmaxf(fmaxf(smax[0], smax[1]), fmaxf(smax[2], smax[3])),
                        fmaxf(fmaxf(smax[4], smax[5]), fmaxf(smax[6], smax[7])));
        const float inv_m = hw_rcp(m + 1.0f);

        // Block-uniform channel params.
        float wk[9];
        #pragma unroll
        for (int k = 0; k < 9; ++k) wk[k] = w1[c * 9 + k];
        const float slope = a1[c];
        const float ww2   = w2[c];
        const float bb2   = b2[c];

        float* outres = out + (size_t)bc * 4096;
        float* outp   = out + N_OUT + (size_t)bc * 4096;

        // Each of 8 waves handles 8 output rows; lane = output col.
        #pragma unroll
        for (int rr = 0; rr < 8; ++rr) {
            const int ho = wid * 8 + rr;
            float xw[3][3];         // [kernel row][col: 2wo-1, 2wo, 2wo+1]
            #pragma unroll
            for (int kr = 0; kr < 3; ++kr) {
                const int hi = 2 * ho - 1 + kr;     // wave-uniform
                float x0 = 0.f, x1 = 0.f, xm = 0.f;
                if ((unsigned)hi < 128u) {
                    float2 v2 = *reinterpret_cast<const float2*>(&plane[hi * 128 + lane * 2]);
                    x0 = v2.x; x1 = v2.y;
                    xm = __shfl_up(x1, 1, 64);      // col 2wo-1
                    if (lane == 0) xm = 0.f;        // zero pad col -1
                }
                xw[kr][0] = xm; xw[kr][1] = x0; xw[kr][2] = x1;
            }

            float v = 0.f;
            #pragma unroll
            for (int kr = 0; kr < 3; ++kr)
                #pragma unroll
                for (int j = 0; j < 3; ++j)
                    v += wk[kr * 3 + j] * xw[kr][j];
            v *= inv_m;
            v = v > 0.f ? v : slope * v;            // PReLU
            float p = v * ww2 + bb2;                // 1x1 dw conv + bias
            p = fminf(fmaxf(p, 1.0f), 110.0f);      // hardtanh

            float s = 0.f;
            #pragma unroll
            for (int kr = 0; kr < 3; ++kr) {
                #pragma unroll
                for (int j = 0; j < 3; ++j) {
                    float x = fmaxf(xw[kr][j], 0.f);
                    float e = hw_exp2(p * hw_log2(x));
                    s += (x > 0.f) ? e : 0.f;
                }
            }
            float mp  = s * (1.0f / 9.0f) + 1e-12f;
            float res = hw_exp2(hw_log2(mp) * hw_rcp(p));

            outres[ho * 64 + lane] = res;
            outp  [ho * 64 + lane] = p;
        }
    }
}

extern "C" void kernel_launch(void* const* d_in, const int* in_sizes, int n_in,
                              void* d_out, int out_size, void* d_ws, size_t ws_size,
                              hipStream_t stream) {
    const float* bottom = (const float*)d_in[0];
    const float* w1     = (const float*)d_in[1];
    const float* a1     = (const float*)d_in[2];
    const float* w2     = (const float*)d_in[3];
    const float* b2     = (const float*)d_in[4];
    float* out = (float*)d_out;

    fused_ppool_pipe<<<2048 / PPB, 512, 0, stream>>>(bottom, w1, a1, w2, b2, out);
}